// Round 2
// baseline (371.934 us; speedup 1.0000x reference)
//
#include <hip/hip_runtime.h>
#include <hip/hip_bf16.h>

#define HID 256
#define QD 64
#define NSEG 16
#define SLQ 2048
#define SLH 2048

typedef __attribute__((ext_vector_type(8))) short bf16x8;
typedef __attribute__((ext_vector_type(8))) __bf16 bf16x8b;
typedef __attribute__((ext_vector_type(4))) float f32x4;

static __device__ __forceinline__ f32x4 mfma16(bf16x8 a, bf16x8 b, f32x4 c) {
  return __builtin_amdgcn_mfma_f32_16x16x32_bf16(
      __builtin_bit_cast(bf16x8b, a), __builtin_bit_cast(bf16x8b, b), c, 0, 0, 0);
}

static __device__ __forceinline__ short f2bf(float x) {
  union { float f; unsigned u; } v; v.f = x;
  unsigned r = v.u + 0x7fffu + ((v.u >> 16) & 1u);
  return (short)(r >> 16);
}

static __device__ __forceinline__ bf16x8 ld8f_bf(const float* p) {
  f32x4 a = *(const f32x4*)p;
  f32x4 b = *(const f32x4*)(p + 4);
  bf16x8 r;
  r[0] = f2bf(a[0]); r[1] = f2bf(a[1]); r[2] = f2bf(a[2]); r[3] = f2bf(a[3]);
  r[4] = f2bf(b[0]); r[5] = f2bf(b[1]); r[6] = f2bf(b[2]); r[7] = f2bf(b[3]);
  return r;
}

__global__ __launch_bounds__(256) void cast_kernel(const float* __restrict__ src,
                                                   short* __restrict__ dst, int n) {
  int i = blockIdx.x * 256 + threadIdx.x;
  if (i < n) dst[i] = f2bf(src[i]);
}

// qq = q @ WQ^T  -> bf16 [32768, 64]
__global__ __launch_bounds__(256) void proj_q_kernel(const float* __restrict__ q,
                                                     const short* __restrict__ wqb,
                                                     short* __restrict__ qq) {
  int wave = threadIdx.x >> 6, lane = threadIdx.x & 63;
  int quad = lane >> 4, l16 = lane & 15;
  int m0 = blockIdx.x * 64 + wave * 16;
  f32x4 acc[4];
#pragma unroll
  for (int n = 0; n < 4; ++n) acc[n] = f32x4{0.f, 0.f, 0.f, 0.f};
#pragma unroll
  for (int ks = 0; ks < 8; ++ks) {
    bf16x8 a = ld8f_bf(q + (size_t)(m0 + l16) * HID + ks * 32 + quad * 8);
#pragma unroll
    for (int n = 0; n < 4; ++n) {
      bf16x8 b = *(const bf16x8*)(wqb + (size_t)(n * 16 + l16) * HID + ks * 32 + quad * 8);
      acc[n] = mfma16(a, b, acc[n]);
    }
  }
#pragma unroll
  for (int n = 0; n < 4; ++n)
#pragma unroll
    for (int r = 0; r < 4; ++r)
      qq[(size_t)(m0 + quad * 4 + r) * QD + n * 16 + l16] = f2bf(acc[n][r]);
}

// k = h @ WK^T -> bf16 [32768,64];  v = h @ WV^T -> transposed vt[seg][dv][tok] bf16
__global__ __launch_bounds__(256) void proj_hv_kernel(const float* __restrict__ h,
                                                      const short* __restrict__ wkb,
                                                      const short* __restrict__ wvb,
                                                      short* __restrict__ kb,
                                                      short* __restrict__ vt) {
  int wave = threadIdx.x >> 6, lane = threadIdx.x & 63;
  int quad = lane >> 4, l16 = lane & 15;
  int m0 = blockIdx.x * 64 + wave * 16;
  f32x4 kacc[4];
  f32x4 vacc[16];
#pragma unroll
  for (int n = 0; n < 4; ++n) kacc[n] = f32x4{0.f, 0.f, 0.f, 0.f};
#pragma unroll
  for (int n = 0; n < 16; ++n) vacc[n] = f32x4{0.f, 0.f, 0.f, 0.f};
#pragma unroll
  for (int ks = 0; ks < 8; ++ks) {
    bf16x8 a = ld8f_bf(h + (size_t)(m0 + l16) * HID + ks * 32 + quad * 8);
#pragma unroll
    for (int n = 0; n < 4; ++n) {
      bf16x8 b = *(const bf16x8*)(wkb + (size_t)(n * 16 + l16) * HID + ks * 32 + quad * 8);
      kacc[n] = mfma16(a, b, kacc[n]);
    }
#pragma unroll
    for (int n = 0; n < 16; ++n) {
      bf16x8 b = *(const bf16x8*)(wvb + (size_t)(n * 16 + l16) * HID + ks * 32 + quad * 8);
      vacc[n] = mfma16(a, b, vacc[n]);
    }
  }
#pragma unroll
  for (int n = 0; n < 4; ++n)
#pragma unroll
    for (int r = 0; r < 4; ++r)
      kb[(size_t)(m0 + quad * 4 + r) * QD + n * 16 + l16] = f2bf(kacc[n][r]);
  int seg = m0 >> 11;
  int tok0 = m0 & 2047;
#pragma unroll
  for (int n = 0; n < 16; ++n)
#pragma unroll
    for (int r = 0; r < 4; ++r) {
      int dv = n * 16 + l16;
      int tok = tok0 + quad * 4 + r;
      vt[((size_t)seg * HID + dv) * SLH + tok] = f2bf(vacc[n][r]);
    }
}

// Flash attention. grid = NSEG*16 blocks (128 q-rows each), 512 threads (8 waves).
__global__ __launch_bounds__(512) void attn_kernel(const short* __restrict__ qq,
                                                   const short* __restrict__ kb,
                                                   const short* __restrict__ vt,
                                                   float* __restrict__ att) {
  __shared__ short p_lds[128][136];  // pad 136: 2-way bank aliasing only (free)
  __shared__ float alpha_lds[128];
  __shared__ float linv_lds[128];
  int wave = threadIdx.x >> 6, lane = threadIdx.x & 63;
  int quad = lane >> 4, l16 = lane & 15;
  int seg = blockIdx.x >> 4, qt = blockIdx.x & 15;
  int qrow0 = seg * SLQ + qt * 128;

  const short* qbase = qq + (size_t)(qrow0 + wave * 16 + l16) * QD + quad * 8;
  bf16x8 qf0 = *(const bf16x8*)qbase;
  bf16x8 qf1 = *(const bf16x8*)(qbase + 32);
  const short* kseg = kb + (size_t)seg * SLH * QD;
  const short* vseg = vt + (size_t)seg * HID * SLH;

  f32x4 o[8][2];
#pragma unroll
  for (int m = 0; m < 8; ++m) {
    o[m][0] = f32x4{0.f, 0.f, 0.f, 0.f};
    o[m][1] = f32x4{0.f, 0.f, 0.f, 0.f};
  }
  float m_i[4], l_i[4];
#pragma unroll
  for (int r = 0; r < 4; ++r) { m_i[r] = -1e30f; l_i[r] = 0.f; }
  const float scale = 0.125f;  // 1/sqrt(64)

  for (int it = 0; it < 16; ++it) {
    int k0 = it * 128;
    // --- S for this wave's 16 rows ---
    f32x4 s[8];
#pragma unroll
    for (int t = 0; t < 8; ++t) {
      const short* kp = kseg + (size_t)(k0 + t * 16 + l16) * QD + quad * 8;
      f32x4 a = f32x4{0.f, 0.f, 0.f, 0.f};
      a = mfma16(qf0, *(const bf16x8*)kp, a);
      a = mfma16(qf1, *(const bf16x8*)(kp + 32), a);
      s[t] = a;
    }
    // --- online softmax (fp32) ---
    float mx[4];
#pragma unroll
    for (int r = 0; r < 4; ++r) {
      float m = s[0][r];
#pragma unroll
      for (int t = 1; t < 8; ++t) m = fmaxf(m, s[t][r]);
      mx[r] = m;
    }
#pragma unroll
    for (int off = 1; off < 16; off <<= 1)
#pragma unroll
      for (int r = 0; r < 4; ++r) mx[r] = fmaxf(mx[r], __shfl_xor(mx[r], off));
    float alpha[4], lsum[4];
#pragma unroll
    for (int r = 0; r < 4; ++r) {
      float mn = fmaxf(m_i[r], mx[r] * scale);
      alpha[r] = __expf(m_i[r] - mn);
      m_i[r] = mn;
      lsum[r] = 0.f;
    }
#pragma unroll
    for (int t = 0; t < 8; ++t)
#pragma unroll
      for (int r = 0; r < 4; ++r) {
        float p = __expf(s[t][r] * scale - m_i[r]);
        lsum[r] += p;
        p_lds[wave * 16 + quad * 4 + r][t * 16 + l16] = f2bf(p);
      }
#pragma unroll
    for (int off = 1; off < 16; off <<= 1)
#pragma unroll
      for (int r = 0; r < 4; ++r) lsum[r] += __shfl_xor(lsum[r], off);
#pragma unroll
    for (int r = 0; r < 4; ++r) l_i[r] = l_i[r] * alpha[r] + lsum[r];
    if (l16 == 0)
#pragma unroll
      for (int r = 0; r < 4; ++r) alpha_lds[wave * 16 + quad * 4 + r] = alpha[r];
    __syncthreads();
    // --- PV: this wave owns dv slice [wave*32, wave*32+32), all 128 rows ---
#pragma unroll
    for (int m = 0; m < 8; ++m)
#pragma unroll
      for (int r = 0; r < 4; ++r) {
        float a = alpha_lds[m * 16 + quad * 4 + r];
        o[m][0][r] *= a;
        o[m][1][r] *= a;
      }
#pragma unroll
    for (int ks = 0; ks < 4; ++ks) {
      bf16x8 pf[8];
#pragma unroll
      for (int m = 0; m < 8; ++m)
        pf[m] = *(const bf16x8*)&p_lds[m * 16 + l16][ks * 32 + quad * 8];
#pragma unroll
      for (int n = 0; n < 2; ++n) {
        const short* vp = vseg + (size_t)(wave * 32 + n * 16 + l16) * SLH + k0 + ks * 32 + quad * 8;
        bf16x8 vf = *(const bf16x8*)vp;
#pragma unroll
        for (int m = 0; m < 8; ++m) o[m][n] = mfma16(pf[m], vf, o[m][n]);
      }
    }
    __syncthreads();
  }
  if (l16 == 0)
#pragma unroll
    for (int r = 0; r < 4; ++r) linv_lds[wave * 16 + quad * 4 + r] = 1.f / l_i[r];
  __syncthreads();
#pragma unroll
  for (int m = 0; m < 8; ++m)
#pragma unroll
    for (int r = 0; r < 4; ++r) {
      int lrow = m * 16 + quad * 4 + r;
      float inv = linv_lds[lrow];
      size_t base = (size_t)(qrow0 + lrow) * HID + wave * 32 + l16;
      att[base] = o[m][0][r] * inv;
      att[base + 16] = o[m][1][r] * inv;
    }
}

// x = LN(q + att); writes x fp32 in-place over att.
__global__ __launch_bounds__(256) void ln1_kernel(const float* __restrict__ qin,
                                                  float* __restrict__ xatt,
                                                  const float* __restrict__ w,
                                                  const float* __restrict__ bia) {
  int wave = threadIdx.x >> 6, lane = threadIdx.x & 63;
  int row = blockIdx.x * 4 + wave;
  float* ap = xatt + (size_t)row * HID + lane * 4;
  const float* qp = qin + (size_t)row * HID + lane * 4;
  f32x4 a = *(const f32x4*)ap;
  f32x4 q4 = *(const f32x4*)qp;
  f32x4 y;
#pragma unroll
  for (int i = 0; i < 4; ++i) y[i] = a[i] + q4[i];
  float s = y[0] + y[1] + y[2] + y[3];
  float s2 = y[0] * y[0] + y[1] * y[1] + y[2] * y[2] + y[3] * y[3];
#pragma unroll
  for (int off = 1; off < 64; off <<= 1) {
    s += __shfl_xor(s, off);
    s2 += __shfl_xor(s2, off);
  }
  float mean = s * (1.f / HID);
  float var = s2 * (1.f / HID) - mean * mean;
  float rstd = rsqrtf(var + 1e-5f);
  f32x4 w4 = *(const f32x4*)(w + lane * 4);
  f32x4 b4 = *(const f32x4*)(bia + lane * 4);
  f32x4 xo;
#pragma unroll
  for (int i = 0; i < 4; ++i) xo[i] = (y[i] - mean) * rstd * w4[i] + b4[i];
  *(f32x4*)ap = xo;
}

// out = LN(x + relu(x@fc_w^T + fc_b)); A-fragments cast from fp32 x on the fly.
__global__ __launch_bounds__(256) void fc_ln_kernel(const float* __restrict__ x,
                                                    const short* __restrict__ fwb,
                                                    const float* __restrict__ fcb,
                                                    const float* __restrict__ w1,
                                                    const float* __restrict__ b1,
                                                    float* __restrict__ out) {
  int wave = threadIdx.x >> 6, lane = threadIdx.x & 63;
  int quad = lane >> 4, l16 = lane & 15;
  int m0 = blockIdx.x * 64 + wave * 16;
  f32x4 acc[16];
#pragma unroll
  for (int n = 0; n < 16; ++n) acc[n] = f32x4{0.f, 0.f, 0.f, 0.f};
#pragma unroll
  for (int ks = 0; ks < 8; ++ks) {
    bf16x8 a = ld8f_bf(x + (size_t)(m0 + l16) * HID + ks * 32 + quad * 8);
#pragma unroll
    for (int n = 0; n < 16; ++n) {
      bf16x8 b = *(const bf16x8*)(fwb + (size_t)(n * 16 + l16) * HID + ks * 32 + quad * 8);
      acc[n] = mfma16(a, b, acc[n]);
    }
  }
#pragma unroll
  for (int r = 0; r < 4; ++r) {
    int row = m0 + quad * 4 + r;
    float yv[16];
    float s = 0.f, s2 = 0.f;
#pragma unroll
    for (int n = 0; n < 16; ++n) {
      int col = n * 16 + l16;
      float hres = acc[n][r] + fcb[col];
      hres = fmaxf(hres, 0.f);
      float y = x[(size_t)row * HID + col] + hres;
      yv[n] = y;
      s += y;
      s2 += y * y;
    }
#pragma unroll
    for (int off = 1; off < 16; off <<= 1) {
      s += __shfl_xor(s, off);
      s2 += __shfl_xor(s2, off);
    }
    float mean = s * (1.f / HID);
    float var = s2 * (1.f / HID) - mean * mean;
    float rstd = rsqrtf(var + 1e-5f);
#pragma unroll
    for (int n = 0; n < 16; ++n) {
      int col = n * 16 + l16;
      out[(size_t)row * HID + col] = (yv[n] - mean) * rstd * w1[col] + b1[col];
    }
  }
}

extern "C" void kernel_launch(void* const* d_in, const int* in_sizes, int n_in,
                              void* d_out, int out_size, void* d_ws, size_t ws_size,
                              hipStream_t stream) {
  const float* q = (const float*)d_in[0];
  const float* h = (const float*)d_in[1];
  const float* WQ = (const float*)d_in[2];
  const float* WK = (const float*)d_in[3];
  const float* WV = (const float*)d_in[4];
  const float* fc_w = (const float*)d_in[5];
  const float* fc_b = (const float*)d_in[6];
  const float* n0w = (const float*)d_in[7];
  const float* n0b = (const float*)d_in[8];
  const float* n1w = (const float*)d_in[9];
  const float* n1b = (const float*)d_in[10];

  char* ws = (char*)d_ws;
  short* qq = (short*)(ws);                            //  4 MB  [0,4)
  short* kb = (short*)(ws + ((size_t)4 << 20));        //  4 MB  [4,8)
  short* vt = (short*)(ws + ((size_t)8 << 20));        // 16 MB  [8,24)
  float* att = (float*)(ws + ((size_t)24 << 20));      // 32 MB  [24,56) — att, then x fp32
  short* wqb = (short*)(ws + ((size_t)56 << 20));
  short* wkb = (short*)(ws + ((size_t)56 << 20) + 32 * 1024);
  short* wvb = (short*)(ws + ((size_t)56 << 20) + 64 * 1024);
  short* fwb = (short*)(ws + ((size_t)56 << 20) + 192 * 1024);

  cast_kernel<<<64, 256, 0, stream>>>(WQ, wqb, QD * HID);
  cast_kernel<<<64, 256, 0, stream>>>(WK, wkb, QD * HID);
  cast_kernel<<<256, 256, 0, stream>>>(WV, wvb, HID * HID);
  cast_kernel<<<256, 256, 0, stream>>>(fc_w, fwb, HID * HID);
  proj_q_kernel<<<512, 256, 0, stream>>>(q, wqb, qq);
  proj_hv_kernel<<<512, 256, 0, stream>>>(h, wkb, wvb, kb, vt);
  attn_kernel<<<NSEG * 16, 512, 0, stream>>>(qq, kb, vt, att);
  ln1_kernel<<<8192, 256, 0, stream>>>(q, att, n0w, n0b);
  fc_ln_kernel<<<512, 256, 0, stream>>>(att, fwb, fc_b, n1w, n1b, (float*)d_out);
}